// Round 5
// baseline (308.782 us; speedup 1.0000x reference)
//
#include <hip/hip_runtime.h>

// MultiheadSelfAttention: x(2,2048,1024) f32 -> QKV proj + RoPE -> causal attn -> out proj
// Round 5: attn = zero-LDS zero-barrier 1-wave blocks; direct-global K/V fragment
//          loads (L2-resident); swapped QK^T, in-lane P via kinv row mapping;
//          defer-max; setprio. GEMMs unchanged (m97-style 128x128).

#define BATCH 2
#define SEQ   2048
#define NH    16
#define HD    64
#define DM    1024
#define MTOT  (BATCH*SEQ)   // 4096

typedef __attribute__((ext_vector_type(8))) short bf16x8;
typedef __attribute__((ext_vector_type(4))) float f32x4;
typedef __attribute__((ext_vector_type(4))) unsigned int u32x4;
typedef unsigned short u16;
typedef unsigned int   u32;

__device__ __forceinline__ float b2f(u16 h){ return __uint_as_float(((u32)h) << 16); }
__device__ __forceinline__ u16 f2b(float f){
  u32 u = __float_as_uint(f);
  u32 r = (u + 0x7FFFu + ((u >> 16) & 1u)) >> 16;   // RNE
  return (u16)r;
}
__device__ __forceinline__ u32 pk2(float lo, float hi){
  return (u32)f2b(lo) | ((u32)f2b(hi) << 16);
}
__device__ __forceinline__ f32x4 mfma16(bf16x8 a, bf16x8 b, f32x4 c){
  return __builtin_amdgcn_mfma_f32_16x16x32_bf16(a, b, c, 0, 0, 0);
}
__device__ __forceinline__ void gload_lds16(const u16* g, u16* l){
  __builtin_amdgcn_global_load_lds((const __attribute__((address_space(1))) unsigned int*)g,
                                   (__attribute__((address_space(3))) unsigned int*)l, 16, 0, 0);
}

// ---------------- fp32 -> bf16 conversion for x and the 4 weights ----------------
__global__ __launch_bounds__(256) void cvt_all(const float* __restrict__ x,
    const float* __restrict__ wq, const float* __restrict__ wk,
    const float* __restrict__ wv, const float* __restrict__ wo,
    u16* __restrict__ xb, u16* __restrict__ wb)
{
  const long NX = (long)MTOT * DM;       // 4194304
  const long NW = (long)DM * DM;         // 1048576
  const long tot4 = (NX + 4*NW) >> 2;
  for (long t = (long)blockIdx.x*blockDim.x + threadIdx.x; t < tot4;
       t += (long)gridDim.x*blockDim.x){
    long e = t << 2;
    const float* s; u16* d;
    if (e < NX){ s = x + e; d = xb + e; }
    else {
      long j = e - NX; int z = (int)(j >> 20);
      const float* ws = (z==0)?wq:(z==1)?wk:(z==2)?wv:wo;
      s = ws + (j & (NW-1)); d = wb + j;
    }
    float4 v = *(const float4*)s;
    u32 lo = (u32)f2b(v.x) | ((u32)f2b(v.y) << 16);
    u32 hi = (u32)f2b(v.z) | ((u32)f2b(v.w) << 16);
    uint2 o; o.x = lo; o.y = hi;
    *(uint2*)d = o;
  }
}

// ---------------- RoPE cos/sin table: [SEQ][32] float2 ----------------
__global__ __launch_bounds__(256) void rope_table(float2* __restrict__ tab){
  int t = blockIdx.x*blockDim.x + threadIdx.x;
  if (t >= SEQ*32) return;
  int s = t >> 5, i = t & 31;
  float inv = 1.0f / powf(10000.0f, (float)i * (1.0f/32.0f));
  float a = (float)s * inv;
  tab[t] = make_float2(cosf(a), sinf(a));
}

// ---------------- m97-style GEMM core: 128x128 tile, BK=32, 4 waves ----------------
__device__ __forceinline__ void gemm128_core(const u16* __restrict__ A, const u16* __restrict__ B,
    int mbase, int nbase, u16* Alds, u16* Blds, f32x4 acc[4][4])
{
  const int tid = threadIdx.x;
  const int w = tid >> 6, l = tid & 63, g = l >> 4, c = l & 15;
  const int wr = (w >> 1)*64, wc = (w & 1)*64;
  const int srow = l >> 2, scol = (l & 3)*8;
  const u16* Ag = A + (long)(mbase + w*32 + srow)*DM + scol;
  const u16* Bg = B + (long)(nbase + w*32 + srow)*DM + scol;
  u16* Alb = Alds + (w*2)*512;
  u16* Blb = Blds + (w*2)*512;

  for (int k0 = 0; k0 < DM; k0 += 32){
    __syncthreads();
    gload_lds16(Ag + k0,           Alb);
    gload_lds16(Ag + 16L*DM + k0,  Alb + 512);
    gload_lds16(Bg + k0,           Blb);
    gload_lds16(Bg + 16L*DM + k0,  Blb + 512);
    __syncthreads();
    bf16x8 af[4], bfr[4];
    #pragma unroll
    for (int mi = 0; mi < 4; mi++) af[mi]  = *(const bf16x8*)&Alds[(wr + mi*16 + c)*32 + g*8];
    #pragma unroll
    for (int nj = 0; nj < 4; nj++) bfr[nj] = *(const bf16x8*)&Blds[(wc + nj*16 + c)*32 + g*8];
    #pragma unroll
    for (int mi = 0; mi < 4; mi++)
      #pragma unroll
      for (int nj = 0; nj < 4; nj++)
        acc[mi][nj] = mfma16(af[mi], bfr[nj], acc[mi][nj]);
  }
}

__global__ __launch_bounds__(256) void gemm_qkv(const u16* __restrict__ xb,
                                                const u16* __restrict__ wb,
                                                u16* __restrict__ qkvr)
{
  __shared__ u16 Alds[128*32];
  __shared__ u16 Blds[128*32];
  const int z = blockIdx.z;
  const u16* Bm = wb + (long)z * DM * DM;
  u16* C = qkvr + (long)z * MTOT * DM;
  const int nbase = blockIdx.x*128, mbase = blockIdx.y*128;
  const int w = threadIdx.x >> 6, l = threadIdx.x & 63, g = l >> 4, c = l & 15;
  const int wr = (w >> 1)*64, wc = (w & 1)*64;
  f32x4 acc[4][4] = {};
  gemm128_core(xb, Bm, mbase, nbase, Alds, Blds, acc);
  #pragma unroll
  for (int mi = 0; mi < 4; mi++)
    #pragma unroll
    for (int nj = 0; nj < 4; nj++)
      #pragma unroll
      for (int r = 0; r < 4; r++){
        int row = mbase + wr + mi*16 + 4*g + r;
        int col = nbase + wc + nj*16 + c;
        C[(long)row*DM + col] = f2b(acc[mi][nj][r]);
      }
}

__global__ __launch_bounds__(256) void gemm_out(const u16* __restrict__ Zb,
                                                const u16* __restrict__ wob,
                                                float* __restrict__ out)
{
  __shared__ u16 Alds[128*32];
  __shared__ u16 Blds[128*32];
  const int nbase = blockIdx.x*128, mbase = blockIdx.y*128;
  const int w = threadIdx.x >> 6, l = threadIdx.x & 63, g = l >> 4, c = l & 15;
  const int wr = (w >> 1)*64, wc = (w & 1)*64;
  f32x4 acc[4][4] = {};
  gemm128_core(Zb, wob, mbase, nbase, Alds, Blds, acc);
  #pragma unroll
  for (int mi = 0; mi < 4; mi++)
    #pragma unroll
    for (int nj = 0; nj < 4; nj++)
      #pragma unroll
      for (int r = 0; r < 4; r++){
        int row = mbase + wr + mi*16 + 4*g + r;
        int col = nbase + wc + nj*16 + c;
        out[(long)row*DM + col] = acc[mi][nj][r];
      }
}

// ---------------- RoPE apply + scatter to attention layouts ----------------
__global__ __launch_bounds__(256) void rope_scatter(const u16* __restrict__ qkvr,
    u16* __restrict__ Qd, u16* __restrict__ Kd, u16* __restrict__ Vt,
    const float2* __restrict__ tab, const int* __restrict__ pos)
{
  int st = blockIdx.x, h = blockIdx.y, b = blockIdx.z;
  int s0 = st*64;
  const u16* Qraw = qkvr;
  const u16* Kraw = qkvr + (long)MTOT*DM;
  const u16* Vraw = qkvr + 2L*MTOT*DM;

  for (int t = threadIdx.x; t < 64*32; t += 256){
    int sl = t >> 5, i = t & 31;
    int s = s0 + sl;
    int p = pos[b*SEQ + s];
    if (p < 0) p = 0; if (p >= SEQ) p = SEQ - 1;
    float2 cs = tab[p*32 + i];
    long inoff  = (long)(b*SEQ + s)*DM + h*HD + 2*i;
    long outoff = ((long)(b*NH + h)*SEQ + s)*HD + 2*i;
    u32 qe = *(const u32*)(Qraw + inoff);
    float x1 = b2f((u16)(qe & 0xffff)), x2 = b2f((u16)(qe >> 16));
    float r1 = x1*cs.x - x2*cs.y;
    float r2 = x1*cs.y + x2*cs.x;
    *(u32*)(Qd + outoff) = (u32)f2b(r1) | ((u32)f2b(r2) << 16);
    u32 ke = *(const u32*)(Kraw + inoff);
    x1 = b2f((u16)(ke & 0xffff)); x2 = b2f((u16)(ke >> 16));
    r1 = x1*cs.x - x2*cs.y;
    r2 = x1*cs.y + x2*cs.x;
    *(u32*)(Kd + outoff) = (u32)f2b(r1) | ((u32)f2b(r2) << 16);
  }

  __shared__ u16 vt[64][65];
  for (int t = threadIdx.x; t < 64*8; t += 256){
    int sl = t >> 3, ch = (t & 7)*8;
    bf16x8 v = *(const bf16x8*)(Vraw + (long)(b*SEQ + s0 + sl)*DM + h*HD + ch);
    #pragma unroll
    for (int j = 0; j < 8; j++) vt[sl][ch + j] = (u16)v[j];
  }
  __syncthreads();
  for (int t = threadIdx.x; t < 64*8; t += 256){
    int d = t >> 3, ch = (t & 7)*8;
    bf16x8 v;
    #pragma unroll
    for (int j = 0; j < 8; j++) v[j] = (short)vt[ch + j][d];
    *(bf16x8*)(Vt + ((long)(b*NH + h)*HD + d)*SEQ + s0 + ch) = v;
  }
}

// ---------------- causal flash attention -----------------------------------
// 1 wave per block, 16 queries/wave, KVBLK=64. No LDS, no barriers.
// Swapped QK^T: S^T = mfma(K,Q), lane owns query q=qbase+c with 16 key-scores
// in regs; K rows read directly from global at kinv(stored_row) so P slots
// are exactly the PV A-frag chunks (keys 8g..8g+7 / 32+8g..+7 in-lane).
// kinv(s) = inverse of kperm: a5=s5, a2=s4, a4=s3, a3=s2, a1=s1, a0=s0.
__device__ __forceinline__ int kinv(int s){
  return (s & 32) | ((s & 16) >> 2) | ((s & 12) << 1) | (s & 3);
}

__global__ __launch_bounds__(64) void attn(const u16* __restrict__ Q, const u16* __restrict__ K,
                                           const u16* __restrict__ Vt, u16* __restrict__ Z)
{
  const int qt = 127 - (int)blockIdx.x;   // longest first
  const int h = blockIdx.y, b = blockIdx.z;
  const int qbase = qt*16;
  const int l = threadIdx.x, g = l >> 4, c = l & 15;
  const u16* Qp = Q  + ((long)(b*NH + h)*SEQ + qbase)*HD;
  const u16* Kp = K  + (long)(b*NH + h)*SEQ*HD;
  const u16* Vp = Vt + (long)(b*NH + h)*HD*SEQ;

  // Q B-fragments: col=c -> query qbase+c, d-chunks g*8 and 32+g*8
  bf16x8 qf0 = *(const bf16x8*)(Qp + c*HD + g*8);
  bf16x8 qf1 = *(const bf16x8*)(Qp + c*HD + 32 + g*8);

  // per-sub actual K row (within tile) this lane reads as A-frag row c
  int arow[4];
  #pragma unroll
  for (int sub = 0; sub < 4; sub++) arow[sub] = kinv(sub*16 + c);

  f32x4 accz[4] = {};
  float m = -1e30f, lsum = 0.f;

  const int ntiles = (qt >> 2) + 1;
  for (int t = 0; t < ntiles; ++t){
    const int kbase = t*64;

    // QK^T (swapped): s[sub][r] = S[key = kbase+32*(sub>>1)+8g+4*(sub&1)+r][q]
    f32x4 s[4];
    __builtin_amdgcn_s_setprio(1);
    #pragma unroll
    for (int sub = 0; sub < 4; sub++){
      const u16* kp = Kp + (long)(kbase + arow[sub])*HD + g*8;
      bf16x8 ka0 = *(const bf16x8*)(kp);
      bf16x8 ka1 = *(const bf16x8*)(kp + 32);
      f32x4 z4 = {};
      z4 = mfma16(ka0, qf0, z4);
      z4 = mfma16(ka1, qf1, z4);
      s[sub] = z4;
    }
    __builtin_amdgcn_s_setprio(0);

    // scale + causal mask (actual key from permutation map)
    const bool edge = (kbase + 63 > qbase);
    const int q = qbase + c;
    #pragma unroll
    for (int sub = 0; sub < 4; sub++)
      #pragma unroll
      for (int r = 0; r < 4; r++){
        float v = s[sub][r]*0.125f;
        if (edge){
          int key = kbase + ((sub >> 1) << 5) + 8*g + ((sub & 1) << 2) + r;
          if (key > q) v = -1e30f;
        }
        s[sub][r] = v;
      }

    // online softmax: 16 in-lane values for query q; reduce across g via 2 shfl
    float tmax = s[0][0];
    #pragma unroll
    for (int sub = 0; sub < 4; sub++)
      #pragma unroll
      for (int r = 0; r < 4; r++) tmax = fmaxf(tmax, s[sub][r]);
    tmax = fmaxf(tmax, __shfl_xor(tmax, 16));
    tmax = fmaxf(tmax, __shfl_xor(tmax, 32));

    // defer-max (T13): only rescale when some row grew past m+8
    if (!__all(tmax <= m + 8.f)){
      float nm = fmaxf(m, tmax);
      float f = __expf(m - nm);
      m = nm;
      lsum *= f;
      float f_bc[4];
      #pragma unroll
      for (int r = 0; r < 4; r++) f_bc[r] = __shfl(f, 4*g + r);
      #pragma unroll
      for (int dt = 0; dt < 4; dt++)
        #pragma unroll
        for (int r = 0; r < 4; r++) accz[dt][r] *= f_bc[r];
    }

    float psum = 0.f;
    #pragma unroll
    for (int sub = 0; sub < 4; sub++)
      #pragma unroll
      for (int r = 0; r < 4; r++){
        float e = __expf(s[sub][r] - m);
        s[sub][r] = e;
        psum += e;
      }
    psum += __shfl_xor(psum, 16);
    psum += __shfl_xor(psum, 32);
    lsum += psum;

    // P -> bf16 A-frags, fully in-lane (keys 8g..8g+7 and 32+8g..+7)
    u32x4 p0, p1;
    p0[0] = pk2(s[0][0], s[0][1]); p0[1] = pk2(s[0][2], s[0][3]);
    p0[2] = pk2(s[1][0], s[1][1]); p0[3] = pk2(s[1][2], s[1][3]);
    p1[0] = pk2(s[2][0], s[2][1]); p1[1] = pk2(s[2][2], s[2][3]);
    p1[2] = pk2(s[3][0], s[3][1]); p1[3] = pk2(s[3][2], s[3][3]);
    bf16x8 pf0 = __builtin_bit_cast(bf16x8, p0);
    bf16x8 pf1 = __builtin_bit_cast(bf16x8, p1);

    // PV: Z[q=4g+r][d=dt*16+c] += P[q][k] V[k][d], V read direct from global
    __builtin_amdgcn_s_setprio(1);
    #pragma unroll
    for (int dt = 0; dt < 4; dt++){
      const u16* vp = Vp + (long)(dt*16 + c)*SEQ + kbase + g*8;
      bf16x8 vf0 = *(const bf16x8*)(vp);
      bf16x8 vf1 = *(const bf16x8*)(vp + 32);
      accz[dt] = mfma16(pf0, vf0, accz[dt]);
      accz[dt] = mfma16(pf1, vf1, accz[dt]);
    }
    __builtin_amdgcn_s_setprio(0);
  }

  // epilogue: lsum lives at lane (g, q-c); broadcast to output-row owners
  float lsum_bc[4];
  #pragma unroll
  for (int r = 0; r < 4; r++) lsum_bc[r] = __shfl(lsum, 4*g + r);
  #pragma unroll
  for (int dt = 0; dt < 4; dt++)
    #pragma unroll
    for (int r = 0; r < 4; r++){
      float zv = accz[dt][r] / lsum_bc[r];
      int row = qbase + 4*g + r;
      int col = dt*16 + c;
      Z[(long)(b*SEQ + row)*DM + h*HD + col] = f2b(zv);
    }
}

extern "C" void kernel_launch(void* const* d_in, const int* in_sizes, int n_in,
                              void* d_out, int out_size, void* d_ws, size_t ws_size,
                              hipStream_t stream)
{
  const float* x  = (const float*)d_in[0];
  const int*   pos= (const int*)d_in[1];
  const float* wq = (const float*)d_in[2];
  const float* wk = (const float*)d_in[3];
  const float* wv = (const float*)d_in[4];
  const float* wo = (const float*)d_in[5];
  float* out = (float*)d_out;

  const long NX = (long)MTOT*DM;
  const long NW = (long)DM*DM;
  char* p = (char*)d_ws;
  u16* xb   = (u16*)p;  p += NX*2;
  u16* wb   = (u16*)p;  p += 4*NW*2;
  u16* qkvr = (u16*)p;  p += 3*NX*2;
  u16* Qd   = (u16*)p;  p += NX*2;
  u16* Kd   = (u16*)p;  p += NX*2;
  u16* Vt   = (u16*)p;  p += NX*2;
  u16* Zb   = (u16*)p;  p += NX*2;
  float2* tab = (float2*)p; p += (long)SEQ*32*sizeof(float2);
  (void)ws_size; (void)n_in; (void)in_sizes; (void)out_size;

  hipLaunchKernelGGL(cvt_all,     dim3(2048),      dim3(256), 0, stream, x, wq, wk, wv, wo, xb, wb);
  hipLaunchKernelGGL(rope_table,  dim3(256),       dim3(256), 0, stream, tab);
  hipLaunchKernelGGL(gemm_qkv,    dim3(8,32,3),    dim3(256), 0, stream, xb, wb, qkvr);
  hipLaunchKernelGGL(rope_scatter,dim3(32,16,2),   dim3(256), 0, stream, qkvr, Qd, Kd, Vt, tab, pos);
  hipLaunchKernelGGL(attn,        dim3(128,16,2),  dim3(64),  0, stream, Qd, Kd, Vt, Zb);
  hipLaunchKernelGGL(gemm_out,    dim3(8,32),      dim3(256), 0, stream, Zb, wb + 3*NW, out);
}

// Round 6
// 156.737 us; speedup vs baseline: 1.9701x; 1.9701x over previous
//
#include <hip/hip_runtime.h>
#include <hip/hip_bf16.h>

// MultiheadSelfAttention: x(2,2048,1024) f32 -> QKV proj + RoPE -> causal attn -> out proj
// Round 6: attn = R3 structure (4-wave QBLK=64, kperm/swizzle LDS, T14 dbuf, 1 barrier)
//          + VALU trims only: compiler bf16 cvt for P-pack, defer-max, setprio.

#define BATCH 2
#define SEQ   2048
#define NH    16
#define HD    64
#define DM    1024
#define MTOT  (BATCH*SEQ)   // 4096

typedef __attribute__((ext_vector_type(8))) short bf16x8;
typedef __attribute__((ext_vector_type(4))) float f32x4;
typedef __attribute__((ext_vector_type(4))) unsigned int u32x4;
typedef unsigned short u16;
typedef unsigned int   u32;

__device__ __forceinline__ float b2f(u16 h){ return __uint_as_float(((u32)h) << 16); }
__device__ __forceinline__ u16 f2b(float f){
  u32 u = __float_as_uint(f);
  u32 r = (u + 0x7FFFu + ((u >> 16) & 1u)) >> 16;   // RNE
  return (u16)r;
}
// compiler-scheduled f32->bf16 (RNE via HW cvt; m240: don't hand-write cvt_pk)
__device__ __forceinline__ u16 cvt1(float f){
  __hip_bfloat16 h = __float2bfloat16(f);
  return *reinterpret_cast<u16*>(&h);
}
__device__ __forceinline__ u32 pk2(float lo, float hi){
  return (u32)cvt1(lo) | ((u32)cvt1(hi) << 16);
}
__device__ __forceinline__ f32x4 mfma16(bf16x8 a, bf16x8 b, f32x4 c){
  return __builtin_amdgcn_mfma_f32_16x16x32_bf16(a, b, c, 0, 0, 0);
}
__device__ __forceinline__ void gload_lds16(const u16* g, u16* l){
  __builtin_amdgcn_global_load_lds((const __attribute__((address_space(1))) unsigned int*)g,
                                   (__attribute__((address_space(3))) unsigned int*)l, 16, 0, 0);
}

// ---------------- fp32 -> bf16 conversion for x and the 4 weights ----------------
__global__ __launch_bounds__(256) void cvt_all(const float* __restrict__ x,
    const float* __restrict__ wq, const float* __restrict__ wk,
    const float* __restrict__ wv, const float* __restrict__ wo,
    u16* __restrict__ xb, u16* __restrict__ wb)
{
  const long NX = (long)MTOT * DM;       // 4194304
  const long NW = (long)DM * DM;         // 1048576
  const long tot4 = (NX + 4*NW) >> 2;
  for (long t = (long)blockIdx.x*blockDim.x + threadIdx.x; t < tot4;
       t += (long)gridDim.x*blockDim.x){
    long e = t << 2;
    const float* s; u16* d;
    if (e < NX){ s = x + e; d = xb + e; }
    else {
      long j = e - NX; int z = (int)(j >> 20);
      const float* ws = (z==0)?wq:(z==1)?wk:(z==2)?wv:wo;
      s = ws + (j & (NW-1)); d = wb + j;
    }
    float4 v = *(const float4*)s;
    u32 lo = (u32)f2b(v.x) | ((u32)f2b(v.y) << 16);
    u32 hi = (u32)f2b(v.z) | ((u32)f2b(v.w) << 16);
    uint2 o; o.x = lo; o.y = hi;
    *(uint2*)d = o;
  }
}

// ---------------- RoPE cos/sin table: [SEQ][32] float2 ----------------
__global__ __launch_bounds__(256) void rope_table(float2* __restrict__ tab){
  int t = blockIdx.x*blockDim.x + threadIdx.x;
  if (t >= SEQ*32) return;
  int s = t >> 5, i = t & 31;
  float inv = 1.0f / powf(10000.0f, (float)i * (1.0f/32.0f));
  float a = (float)s * inv;
  tab[t] = make_float2(cosf(a), sinf(a));
}

// ---------------- m97-style GEMM core: 128x128 tile, BK=32, 4 waves ----------------
__device__ __forceinline__ void gemm128_core(const u16* __restrict__ A, const u16* __restrict__ B,
    int mbase, int nbase, u16* Alds, u16* Blds, f32x4 acc[4][4])
{
  const int tid = threadIdx.x;
  const int w = tid >> 6, l = tid & 63, g = l >> 4, c = l & 15;
  const int wr = (w >> 1)*64, wc = (w & 1)*64;
  const int srow = l >> 2, scol = (l & 3)*8;
  const u16* Ag = A + (long)(mbase + w*32 + srow)*DM + scol;
  const u16* Bg = B + (long)(nbase + w*32 + srow)*DM + scol;
  u16* Alb = Alds + (w*2)*512;
  u16* Blb = Blds + (w*2)*512;

  for (int k0 = 0; k0 < DM; k0 += 32){
    __syncthreads();
    gload_lds16(Ag + k0,           Alb);
    gload_lds16(Ag + 16L*DM + k0,  Alb + 512);
    gload_lds16(Bg + k0,           Blb);
    gload_lds16(Bg + 16L*DM + k0,  Blb + 512);
    __syncthreads();
    bf16x8 af[4], bfr[4];
    #pragma unroll
    for (int mi = 0; mi < 4; mi++) af[mi]  = *(const bf16x8*)&Alds[(wr + mi*16 + c)*32 + g*8];
    #pragma unroll
    for (int nj = 0; nj < 4; nj++) bfr[nj] = *(const bf16x8*)&Blds[(wc + nj*16 + c)*32 + g*8];
    #pragma unroll
    for (int mi = 0; mi < 4; mi++)
      #pragma unroll
      for (int nj = 0; nj < 4; nj++)
        acc[mi][nj] = mfma16(af[mi], bfr[nj], acc[mi][nj]);
  }
}

__global__ __launch_bounds__(256) void gemm_qkv(const u16* __restrict__ xb,
                                                const u16* __restrict__ wb,
                                                u16* __restrict__ qkvr)
{
  __shared__ u16 Alds[128*32];
  __shared__ u16 Blds[128*32];
  const int z = blockIdx.z;
  const u16* Bm = wb + (long)z * DM * DM;
  u16* C = qkvr + (long)z * MTOT * DM;
  const int nbase = blockIdx.x*128, mbase = blockIdx.y*128;
  const int w = threadIdx.x >> 6, l = threadIdx.x & 63, g = l >> 4, c = l & 15;
  const int wr = (w >> 1)*64, wc = (w & 1)*64;
  f32x4 acc[4][4] = {};
  gemm128_core(xb, Bm, mbase, nbase, Alds, Blds, acc);
  #pragma unroll
  for (int mi = 0; mi < 4; mi++)
    #pragma unroll
    for (int nj = 0; nj < 4; nj++)
      #pragma unroll
      for (int r = 0; r < 4; r++){
        int row = mbase + wr + mi*16 + 4*g + r;
        int col = nbase + wc + nj*16 + c;
        C[(long)row*DM + col] = f2b(acc[mi][nj][r]);
      }
}

__global__ __launch_bounds__(256) void gemm_out(const u16* __restrict__ Zb,
                                                const u16* __restrict__ wob,
                                                float* __restrict__ out)
{
  __shared__ u16 Alds[128*32];
  __shared__ u16 Blds[128*32];
  const int nbase = blockIdx.x*128, mbase = blockIdx.y*128;
  const int w = threadIdx.x >> 6, l = threadIdx.x & 63, g = l >> 4, c = l & 15;
  const int wr = (w >> 1)*64, wc = (w & 1)*64;
  f32x4 acc[4][4] = {};
  gemm128_core(Zb, wob, mbase, nbase, Alds, Blds, acc);
  #pragma unroll
  for (int mi = 0; mi < 4; mi++)
    #pragma unroll
    for (int nj = 0; nj < 4; nj++)
      #pragma unroll
      for (int r = 0; r < 4; r++){
        int row = mbase + wr + mi*16 + 4*g + r;
        int col = nbase + wc + nj*16 + c;
        out[(long)row*DM + col] = acc[mi][nj][r];
      }
}

// ---------------- RoPE apply + scatter to attention layouts ----------------
__global__ __launch_bounds__(256) void rope_scatter(const u16* __restrict__ qkvr,
    u16* __restrict__ Qd, u16* __restrict__ Kd, u16* __restrict__ Vt,
    const float2* __restrict__ tab, const int* __restrict__ pos)
{
  int st = blockIdx.x, h = blockIdx.y, b = blockIdx.z;
  int s0 = st*64;
  const u16* Qraw = qkvr;
  const u16* Kraw = qkvr + (long)MTOT*DM;
  const u16* Vraw = qkvr + 2L*MTOT*DM;

  for (int t = threadIdx.x; t < 64*32; t += 256){
    int sl = t >> 5, i = t & 31;
    int s = s0 + sl;
    int p = pos[b*SEQ + s];
    if (p < 0) p = 0; if (p >= SEQ) p = SEQ - 1;
    float2 cs = tab[p*32 + i];
    long inoff  = (long)(b*SEQ + s)*DM + h*HD + 2*i;
    long outoff = ((long)(b*NH + h)*SEQ + s)*HD + 2*i;
    u32 qe = *(const u32*)(Qraw + inoff);
    float x1 = b2f((u16)(qe & 0xffff)), x2 = b2f((u16)(qe >> 16));
    float r1 = x1*cs.x - x2*cs.y;
    float r2 = x1*cs.y + x2*cs.x;
    *(u32*)(Qd + outoff) = (u32)f2b(r1) | ((u32)f2b(r2) << 16);
    u32 ke = *(const u32*)(Kraw + inoff);
    x1 = b2f((u16)(ke & 0xffff)); x2 = b2f((u16)(ke >> 16));
    r1 = x1*cs.x - x2*cs.y;
    r2 = x1*cs.y + x2*cs.x;
    *(u32*)(Kd + outoff) = (u32)f2b(r1) | ((u32)f2b(r2) << 16);
  }

  __shared__ u16 vt[64][65];
  for (int t = threadIdx.x; t < 64*8; t += 256){
    int sl = t >> 3, ch = (t & 7)*8;
    bf16x8 v = *(const bf16x8*)(Vraw + (long)(b*SEQ + s0 + sl)*DM + h*HD + ch);
    #pragma unroll
    for (int j = 0; j < 8; j++) vt[sl][ch + j] = (u16)v[j];
  }
  __syncthreads();
  for (int t = threadIdx.x; t < 64*8; t += 256){
    int d = t >> 3, ch = (t & 7)*8;
    bf16x8 v;
    #pragma unroll
    for (int j = 0; j < 8; j++) v[j] = (short)vt[ch + j][d];
    *(bf16x8*)(Vt + ((long)(b*NH + h)*HD + d)*SEQ + s0 + ch) = v;
  }
}

// ---------------- causal flash attention -----------------------------------
// 4 waves, QBLK=64 (16 q/wave), KVBLK=64. Swapped QK^T: lane owns query q=c,
// 16 key-scores in regs; K rows permuted in LDS (kperm) so P stays in-lane;
// XOR-swizzled K/V LDS (0 bank conflicts); T14 async dbuf, 1 barrier/tile;
// defer-max (T13); setprio (T5); compiler-cvt P-pack.
__device__ __forceinline__ int kperm(int a){
  return (a & 32) | ((a & 4) << 2) | ((a & 24) >> 1) | (a & 3);
}

__global__ __launch_bounds__(256) void attn(const u16* __restrict__ Q, const u16* __restrict__ K,
                                            const u16* __restrict__ Vt, u16* __restrict__ Z)
{
  const int qt = (int)gridDim.x - 1 - (int)blockIdx.x;   // longest first
  const int h = blockIdx.y, b = blockIdx.z;
  const int qbase = qt*64;
  const int tid = threadIdx.x, w = tid >> 6, l = tid & 63, g = l >> 4, c = l & 15;
  const int qrow = qbase + w*16;   // this wave's 16 q-rows
  const u16* Qp = Q  + ((long)(b*NH + h)*SEQ + qrow)*HD;
  const u16* Kp = K  + (long)(b*NH + h)*SEQ*HD;
  const u16* Vp = Vt + (long)(b*NH + h)*HD*SEQ;

  __shared__ u16 K_lds[2][64][64];
  __shared__ u16 V_lds[2][64][64];

  // Q B-fragments: col=c -> query qrow+c, d-chunks g*8 and 32+g*8
  bf16x8 qf0 = *(const bf16x8*)(Qp + c*HD + g*8);
  bf16x8 qf1 = *(const bf16x8*)(Qp + c*HD + 32 + g*8);

  // staging: thread covers (row = u>>3, chunk = u&7) for u = tid, tid+256
  const int srow0 = tid >> 3, sch = tid & 7;
  const int kpr0 = kperm(srow0), kpr1 = kperm(srow0 + 32);

  f32x4 accz[4] = {};
  float m = -1e30f, lsum = 0.f;
  const int cswz = c & 7;

  bf16x8 kr[2], vr[2];
  // prologue: tile 0 -> regs -> LDS buf 0
  #pragma unroll
  for (int i = 0; i < 2; i++){
    int row = srow0 + i*32;
    kr[i] = *(const bf16x8*)(Kp + (long)row*HD + sch*8);
    vr[i] = *(const bf16x8*)(Vp + (long)row*SEQ + sch*8);
  }
  {
    *(bf16x8*)&K_lds[0][kpr0][(sch ^ (kpr0 & 7))*8] = kr[0];
    *(bf16x8*)&K_lds[0][kpr1][(sch ^ (kpr1 & 7))*8] = kr[1];
    *(bf16x8*)&V_lds[0][srow0][(sch ^ (srow0 & 7))*8] = vr[0];
    *(bf16x8*)&V_lds[0][srow0+32][(sch ^ ((srow0+32) & 7))*8] = vr[1];
  }

  int cur = 0;
  for (int t = 0; t <= qt; ++t){
    const int kbase = t*64;
    __syncthreads();   // buf `cur` ready; all prior reads of cur^1 done

    if (t < qt){       // T14: issue next tile's global loads now, write LDS later
      const int nb = kbase + 64;
      #pragma unroll
      for (int i = 0; i < 2; i++){
        int row = srow0 + i*32;
        kr[i] = *(const bf16x8*)(Kp + (long)(nb + row)*HD + sch*8);
        vr[i] = *(const bf16x8*)(Vp + (long)row*SEQ + nb + sch*8);
      }
    }

    // QK^T (swapped): s[sub][r] = S_stored[sub*16+4g+r][q=c]
    f32x4 s[4];
    __builtin_amdgcn_s_setprio(1);
    #pragma unroll
    for (int sub = 0; sub < 4; sub++){
      int row = sub*16 + c;
      bf16x8 ka0 = *(const bf16x8*)&K_lds[cur][row][((0+g) ^ cswz)*8];
      bf16x8 ka1 = *(const bf16x8*)&K_lds[cur][row][((4+g) ^ cswz)*8];
      f32x4 z4 = {};
      z4 = mfma16(ka0, qf0, z4);
      z4 = mfma16(ka1, qf1, z4);
      s[sub] = z4;
    }
    __builtin_amdgcn_s_setprio(0);

    // scale + causal mask (actual key from permutation map)
    const bool edge = (kbase + 63 > qrow);
    const int q = qrow + c;
    #pragma unroll
    for (int sub = 0; sub < 4; sub++)
      #pragma unroll
      for (int r = 0; r < 4; r++){
        float v = s[sub][r]*0.125f;
        if (edge){
          int key = kbase + ((sub >> 1) << 5) + 8*g + ((sub & 1) << 2) + r;
          if (key > q) v = -1e30f;
        }
        s[sub][r] = v;
      }

    // online softmax: 16 in-lane values for query q=c; reduce across g via 2 shfl
    float tmax = s[0][0];
    #pragma unroll
    for (int sub = 0; sub < 4; sub++)
      #pragma unroll
      for (int r = 0; r < 4; r++) tmax = fmaxf(tmax, s[sub][r]);
    tmax = fmaxf(tmax, __shfl_xor(tmax, 16));
    tmax = fmaxf(tmax, __shfl_xor(tmax, 32));

    // defer-max (T13): only rescale when some row grew past m+8
    if (!__all(tmax <= m + 8.f)){
      float nm = fmaxf(m, tmax);
      float f = __expf(m - nm);
      m = nm;
      lsum *= f;
      float f_bc[4];
      #pragma unroll
      for (int r = 0; r < 4; r++) f_bc[r] = __shfl(f, 4*g + r);
      #pragma unroll
      for (int dt = 0; dt < 4; dt++)
        #pragma unroll
        for (int r = 0; r < 4; r++) accz[dt][r] *= f_bc[r];
    }

    float psum = 0.f;
    #pragma unroll
    for (int sub = 0; sub < 4; sub++)
      #pragma unroll
      for (int r = 0; r < 4; r++){
        float e = __expf(s[sub][r] - m);
        s[sub][r] = e;
        psum += e;
      }
    psum += __shfl_xor(psum, 16);
    psum += __shfl_xor(psum, 32);
    lsum += psum;

    // P -> bf16 A-frags, fully in-lane (keys 8g..8g+7 and 32+8g..+7)
    u32x4 p0, p1;
    p0[0] = pk2(s[0][0], s[0][1]); p0[1] = pk2(s[0][2], s[0][3]);
    p0[2] = pk2(s[1][0], s[1][1]); p0[3] = pk2(s[1][2], s[1][3]);
    p1[0] = pk2(s[2][0], s[2][1]); p1[1] = pk2(s[2][2], s[2][3]);
    p1[2] = pk2(s[3][0], s[3][1]); p1[3] = pk2(s[3][2], s[3][3]);
    bf16x8 pf0 = __builtin_bit_cast(bf16x8, p0);
    bf16x8 pf1 = __builtin_bit_cast(bf16x8, p1);

    // PV: Z[q=4g+r][d=dt*16+c] += P[q][k] V[k][d]
    __builtin_amdgcn_s_setprio(1);
    #pragma unroll
    for (int dt = 0; dt < 4; dt++){
      int vrow = dt*16 + c;
      bf16x8 vf0 = *(const bf16x8*)&V_lds[cur][vrow][((0+g) ^ cswz)*8];
      bf16x8 vf1 = *(const bf16x8*)&V_lds[cur][vrow][((4+g) ^ cswz)*8];
      accz[dt] = mfma16(pf0, vf0, accz[dt]);
      accz[dt] = mfma16(pf1, vf1, accz[dt]);
    }
    __builtin_amdgcn_s_setprio(0);

    if (t < qt){   // write next tile into the other buffer (no barrier needed)
      int nx = cur ^ 1;
      *(bf16x8*)&K_lds[nx][kpr0][(sch ^ (kpr0 & 7))*8] = kr[0];
      *(bf16x8*)&K_lds[nx][kpr1][(sch ^ (kpr1 & 7))*8] = kr[1];
      *(bf16x8*)&V_lds[nx][srow0][(sch ^ (srow0 & 7))*8] = vr[0];
      *(bf16x8*)&V_lds[nx][srow0+32][(sch ^ ((srow0+32) & 7))*8] = vr[1];
      cur = nx;
    }
  }

  // epilogue: lsum lives at lane (0, q); broadcast to output-row owners
  float lsum_bc[4];
  #pragma unroll
  for (int r = 0; r < 4; r++) lsum_bc[r] = __shfl(lsum, 4*g + r);
  #pragma unroll
  for (int dt = 0; dt < 4; dt++)
    #pragma unroll
    for (int r = 0; r < 4; r++){
      float zv = accz[dt][r] / lsum_bc[r];
      int row = qrow + 4*g + r;
      int col = dt*16 + c;
      Z[(long)(b*SEQ + row)*DM + h*HD + col] = cvt1(zv);
    }
}

extern "C" void kernel_launch(void* const* d_in, const int* in_sizes, int n_in,
                              void* d_out, int out_size, void* d_ws, size_t ws_size,
                              hipStream_t stream)
{
  const float* x  = (const float*)d_in[0];
  const int*   pos= (const int*)d_in[1];
  const float* wq = (const float*)d_in[2];
  const float* wk = (const float*)d_in[3];
  const float* wv = (const float*)d_in[4];
  const float* wo = (const float*)d_in[5];
  float* out = (float*)d_out;

  const long NX = (long)MTOT*DM;
  const long NW = (long)DM*DM;
  char* p = (char*)d_ws;
  u16* xb   = (u16*)p;  p += NX*2;
  u16* wb   = (u16*)p;  p += 4*NW*2;
  u16* qkvr = (u16*)p;  p += 3*NX*2;
  u16* Qd   = (u16*)p;  p += NX*2;
  u16* Kd   = (u16*)p;  p += NX*2;
  u16* Vt   = (u16*)p;  p += NX*2;
  u16* Zb   = (u16*)p;  p += NX*2;
  float2* tab = (float2*)p; p += (long)SEQ*32*sizeof(float2);
  (void)ws_size; (void)n_in; (void)in_sizes; (void)out_size;

  hipLaunchKernelGGL(cvt_all,     dim3(2048),      dim3(256), 0, stream, x, wq, wk, wv, wo, xb, wb);
  hipLaunchKernelGGL(rope_table,  dim3(256),       dim3(256), 0, stream, tab);
  hipLaunchKernelGGL(gemm_qkv,    dim3(8,32,3),    dim3(256), 0, stream, xb, wb, qkvr);
  hipLaunchKernelGGL(rope_scatter,dim3(32,16,2),   dim3(256), 0, stream, qkvr, Qd, Kd, Vt, tab, pos);
  hipLaunchKernelGGL(attn,        dim3(32,16,2),   dim3(256), 0, stream, Qd, Kd, Vt, Zb);
  hipLaunchKernelGGL(gemm_out,    dim3(8,32),      dim3(256), 0, stream, Zb, wb + 3*NW, out);
}

// Round 7
// 142.408 us; speedup vs baseline: 2.1683x; 1.1006x over previous
//
#include <hip/hip_runtime.h>
#include <hip/hip_bf16.h>

// MultiheadSelfAttention: x(2,2048,1024) f32 -> QKV proj + RoPE -> causal attn -> out proj
// Round 7: attn QBLK=128/8-wave (half barriers+staging per work);
//          GEMMs BK=64 + T2 XOR-swizzle (pre-swizzled global source, linear LDS dst).

#define BATCH 2
#define SEQ   2048
#define NH    16
#define HD    64
#define DM    1024
#define MTOT  (BATCH*SEQ)   // 4096

typedef __attribute__((ext_vector_type(8))) short bf16x8;
typedef __attribute__((ext_vector_type(4))) float f32x4;
typedef __attribute__((ext_vector_type(4))) unsigned int u32x4;
typedef unsigned short u16;
typedef unsigned int   u32;

__device__ __forceinline__ float b2f(u16 h){ return __uint_as_float(((u32)h) << 16); }
__device__ __forceinline__ u16 f2b(float f){
  u32 u = __float_as_uint(f);
  u32 r = (u + 0x7FFFu + ((u >> 16) & 1u)) >> 16;   // RNE
  return (u16)r;
}
// compiler-scheduled f32->bf16 (m240: don't hand-write cvt_pk)
__device__ __forceinline__ u16 cvt1(float f){
  __hip_bfloat16 h = __float2bfloat16(f);
  return *reinterpret_cast<u16*>(&h);
}
__device__ __forceinline__ u32 pk2(float lo, float hi){
  return (u32)cvt1(lo) | ((u32)cvt1(hi) << 16);
}
__device__ __forceinline__ f32x4 mfma16(bf16x8 a, bf16x8 b, f32x4 c){
  return __builtin_amdgcn_mfma_f32_16x16x32_bf16(a, b, c, 0, 0, 0);
}
__device__ __forceinline__ void gload_lds16(const u16* g, u16* l){
  __builtin_amdgcn_global_load_lds((const __attribute__((address_space(1))) unsigned int*)g,
                                   (__attribute__((address_space(3))) unsigned int*)l, 16, 0, 0);
}

// ---------------- fp32 -> bf16 conversion for x and the 4 weights ----------------
__global__ __launch_bounds__(256) void cvt_all(const float* __restrict__ x,
    const float* __restrict__ wq, const float* __restrict__ wk,
    const float* __restrict__ wv, const float* __restrict__ wo,
    u16* __restrict__ xb, u16* __restrict__ wb)
{
  const long NX = (long)MTOT * DM;       // 4194304
  const long NW = (long)DM * DM;         // 1048576
  const long tot4 = (NX + 4*NW) >> 2;
  for (long t = (long)blockIdx.x*blockDim.x + threadIdx.x; t < tot4;
       t += (long)gridDim.x*blockDim.x){
    long e = t << 2;
    const float* s; u16* d;
    if (e < NX){ s = x + e; d = xb + e; }
    else {
      long j = e - NX; int z = (int)(j >> 20);
      const float* ws = (z==0)?wq:(z==1)?wk:(z==2)?wv:wo;
      s = ws + (j & (NW-1)); d = wb + j;
    }
    float4 v = *(const float4*)s;
    u32 lo = (u32)f2b(v.x) | ((u32)f2b(v.y) << 16);
    u32 hi = (u32)f2b(v.z) | ((u32)f2b(v.w) << 16);
    uint2 o; o.x = lo; o.y = hi;
    *(uint2*)d = o;
  }
}

// ---------------- RoPE cos/sin table: [SEQ][32] float2 ----------------
__global__ __launch_bounds__(256) void rope_table(float2* __restrict__ tab){
  int t = blockIdx.x*blockDim.x + threadIdx.x;
  if (t >= SEQ*32) return;
  int s = t >> 5, i = t & 31;
  float inv = 1.0f / powf(10000.0f, (float)i * (1.0f/32.0f));
  float a = (float)s * inv;
  tab[t] = make_float2(cosf(a), sinf(a));
}

// ---------------- GEMM core: 128x128 tile, BK=64, 4 waves, swizzled LDS -----------
// C[m][n] = sum_k A[m][k]*B[n][k]. LDS [128][64] bf16 (128B rows); T2 swizzle:
// LDS[row][chunk j] holds global 16B-chunk (j ^ (row&7)); achieved by pre-swizzling
// the per-lane GLOBAL column (linear gload_lds dst, rule #21); reads XOR the chunk.
__device__ __forceinline__ void gemm128_core(const u16* __restrict__ A, const u16* __restrict__ B,
    int mbase, int nbase, u16* Alds, u16* Blds, f32x4 acc[4][4])
{
  const int tid = threadIdx.x;
  const int w = tid >> 6, l = tid & 63, g = l >> 4, c = l & 15;
  const int wr = (w >> 1)*64, wc = (w & 1)*64;
  const int srow = l >> 3;                        // 0..7 within 8-row group
  const int scol = ((l & 7) ^ srow)*8;            // pre-swizzled global col chunk
  const u16* Ag = A + (long)(mbase + w*32 + srow)*DM + scol;
  const u16* Bg = B + (long)(nbase + w*32 + srow)*DM + scol;
  u16* Alb = Alds + w*2048;
  u16* Blb = Blds + w*2048;

  for (int k0 = 0; k0 < DM; k0 += 64){
    __syncthreads();
    #pragma unroll
    for (int i = 0; i < 4; i++){
      gload_lds16(Ag + k0 + (long)(8*i)*DM, Alb + i*512);
      gload_lds16(Bg + k0 + (long)(8*i)*DM, Blb + i*512);
    }
    __syncthreads();
    #pragma unroll
    for (int ks = 0; ks < 2; ks++){
      bf16x8 af[4], bfr[4];
      #pragma unroll
      for (int mi = 0; mi < 4; mi++){
        int row = wr + mi*16 + c;
        af[mi] = *(const bf16x8*)&Alds[row*64 + (((ks*4 + g) ^ (row & 7))*8)];
      }
      #pragma unroll
      for (int nj = 0; nj < 4; nj++){
        int row = wc + nj*16 + c;
        bfr[nj] = *(const bf16x8*)&Blds[row*64 + (((ks*4 + g) ^ (row & 7))*8)];
      }
      #pragma unroll
      for (int mi = 0; mi < 4; mi++)
        #pragma unroll
        for (int nj = 0; nj < 4; nj++)
          acc[mi][nj] = mfma16(af[mi], bfr[nj], acc[mi][nj]);
    }
  }
}

__global__ __launch_bounds__(256) void gemm_qkv(const u16* __restrict__ xb,
                                                const u16* __restrict__ wb,
                                                u16* __restrict__ qkvr)
{
  __shared__ u16 Alds[128*64];
  __shared__ u16 Blds[128*64];
  const int z = blockIdx.z;
  const u16* Bm = wb + (long)z * DM * DM;
  u16* C = qkvr + (long)z * MTOT * DM;
  const int nbase = blockIdx.x*128, mbase = blockIdx.y*128;
  const int w = threadIdx.x >> 6, l = threadIdx.x & 63, g = l >> 4, c = l & 15;
  const int wr = (w >> 1)*64, wc = (w & 1)*64;
  f32x4 acc[4][4] = {};
  gemm128_core(xb, Bm, mbase, nbase, Alds, Blds, acc);
  #pragma unroll
  for (int mi = 0; mi < 4; mi++)
    #pragma unroll
    for (int nj = 0; nj < 4; nj++)
      #pragma unroll
      for (int r = 0; r < 4; r++){
        int row = mbase + wr + mi*16 + 4*g + r;
        int col = nbase + wc + nj*16 + c;
        C[(long)row*DM + col] = f2b(acc[mi][nj][r]);
      }
}

__global__ __launch_bounds__(256) void gemm_out(const u16* __restrict__ Zb,
                                                const u16* __restrict__ wob,
                                                float* __restrict__ out)
{
  __shared__ u16 Alds[128*64];
  __shared__ u16 Blds[128*64];
  const int nbase = blockIdx.x*128, mbase = blockIdx.y*128;
  const int w = threadIdx.x >> 6, l = threadIdx.x & 63, g = l >> 4, c = l & 15;
  const int wr = (w >> 1)*64, wc = (w & 1)*64;
  f32x4 acc[4][4] = {};
  gemm128_core(Zb, wob, mbase, nbase, Alds, Blds, acc);
  #pragma unroll
  for (int mi = 0; mi < 4; mi++)
    #pragma unroll
    for (int nj = 0; nj < 4; nj++)
      #pragma unroll
      for (int r = 0; r < 4; r++){
        int row = mbase + wr + mi*16 + 4*g + r;
        int col = nbase + wc + nj*16 + c;
        out[(long)row*DM + col] = acc[mi][nj][r];
      }
}

// ---------------- RoPE apply + scatter to attention layouts ----------------
__global__ __launch_bounds__(256) void rope_scatter(const u16* __restrict__ qkvr,
    u16* __restrict__ Qd, u16* __restrict__ Kd, u16* __restrict__ Vt,
    const float2* __restrict__ tab, const int* __restrict__ pos)
{
  int st = blockIdx.x, h = blockIdx.y, b = blockIdx.z;
  int s0 = st*64;
  const u16* Qraw = qkvr;
  const u16* Kraw = qkvr + (long)MTOT*DM;
  const u16* Vraw = qkvr + 2L*MTOT*DM;

  for (int t = threadIdx.x; t < 64*32; t += 256){
    int sl = t >> 5, i = t & 31;
    int s = s0 + sl;
    int p = pos[b*SEQ + s];
    if (p < 0) p = 0; if (p >= SEQ) p = SEQ - 1;
    float2 cs = tab[p*32 + i];
    long inoff  = (long)(b*SEQ + s)*DM + h*HD + 2*i;
    long outoff = ((long)(b*NH + h)*SEQ + s)*HD + 2*i;
    u32 qe = *(const u32*)(Qraw + inoff);
    float x1 = b2f((u16)(qe & 0xffff)), x2 = b2f((u16)(qe >> 16));
    float r1 = x1*cs.x - x2*cs.y;
    float r2 = x1*cs.y + x2*cs.x;
    *(u32*)(Qd + outoff) = (u32)f2b(r1) | ((u32)f2b(r2) << 16);
    u32 ke = *(const u32*)(Kraw + inoff);
    x1 = b2f((u16)(ke & 0xffff)); x2 = b2f((u16)(ke >> 16));
    r1 = x1*cs.x - x2*cs.y;
    r2 = x1*cs.y + x2*cs.x;
    *(u32*)(Kd + outoff) = (u32)f2b(r1) | ((u32)f2b(r2) << 16);
  }

  __shared__ u16 vt[64][65];
  for (int t = threadIdx.x; t < 64*8; t += 256){
    int sl = t >> 3, ch = (t & 7)*8;
    bf16x8 v = *(const bf16x8*)(Vraw + (long)(b*SEQ + s0 + sl)*DM + h*HD + ch);
    #pragma unroll
    for (int j = 0; j < 8; j++) vt[sl][ch + j] = (u16)v[j];
  }
  __syncthreads();
  for (int t = threadIdx.x; t < 64*8; t += 256){
    int d = t >> 3, ch = (t & 7)*8;
    bf16x8 v;
    #pragma unroll
    for (int j = 0; j < 8; j++) v[j] = (short)vt[ch + j][d];
    *(bf16x8*)(Vt + ((long)(b*NH + h)*HD + d)*SEQ + s0 + ch) = v;
  }
}

// ---------------- causal flash attention -----------------------------------
// 8 waves, QBLK=128 (16 q/wave), KVBLK=64. Swapped QK^T: lane owns query q=c,
// 16 key-scores in regs; K rows permuted in LDS (kperm) so P stays in-lane;
// XOR-swizzled K/V LDS (0 conflicts); T14 async dbuf, 1 barrier/tile;
// defer-max (T13); setprio (T5); compiler-cvt P-pack.
__device__ __forceinline__ int kperm(int a){
  return (a & 32) | ((a & 4) << 2) | ((a & 24) >> 1) | (a & 3);
}

__global__ __launch_bounds__(512) void attn(const u16* __restrict__ Q, const u16* __restrict__ K,
                                            const u16* __restrict__ Vt, u16* __restrict__ Z)
{
  const int qt = 15 - (int)blockIdx.x;   // longest first
  const int h = blockIdx.y, b = blockIdx.z;
  const int qbase = qt*128;
  const int tid = threadIdx.x, w = tid >> 6, l = tid & 63, g = l >> 4, c = l & 15;
  const int qrow = qbase + w*16;   // this wave's 16 q-rows
  const u16* Qp = Q  + ((long)(b*NH + h)*SEQ + qrow)*HD;
  const u16* Kp = K  + (long)(b*NH + h)*SEQ*HD;
  const u16* Vp = Vt + (long)(b*NH + h)*HD*SEQ;

  __shared__ u16 K_lds[2][64][64];
  __shared__ u16 V_lds[2][64][64];

  // Q B-fragments: col=c -> query qrow+c, d-chunks g*8 and 32+g*8
  bf16x8 qf0 = *(const bf16x8*)(Qp + c*HD + g*8);
  bf16x8 qf1 = *(const bf16x8*)(Qp + c*HD + 32 + g*8);

  // staging: 512 threads cover 64 rows x 8 chunks exactly once
  const int srow0 = tid >> 3, sch = tid & 7;
  const int kpr0 = kperm(srow0);

  f32x4 accz[4] = {};
  float m = -1e30f, lsum = 0.f;
  const int cswz = c & 7;

  bf16x8 kr, vr;
  // prologue: tile 0 -> regs -> LDS buf 0
  kr = *(const bf16x8*)(Kp + (long)srow0*HD + sch*8);
  vr = *(const bf16x8*)(Vp + (long)srow0*SEQ + sch*8);
  *(bf16x8*)&K_lds[0][kpr0][(sch ^ (kpr0 & 7))*8] = kr;
  *(bf16x8*)&V_lds[0][srow0][(sch ^ (srow0 & 7))*8] = vr;

  const int ntiles = 2*qt + 2;
  int cur = 0;
  for (int t = 0; t < ntiles; ++t){
    const int kbase = t*64;
    __syncthreads();   // buf `cur` ready; all prior reads of cur^1 done

    if (t < ntiles-1){   // T14: issue next tile's global loads now, write LDS later
      const int nb = kbase + 64;
      kr = *(const bf16x8*)(Kp + (long)(nb + srow0)*HD + sch*8);
      vr = *(const bf16x8*)(Vp + (long)srow0*SEQ + nb + sch*8);
    }

    // QK^T (swapped): s[sub][r] = S_stored[sub*16+4g+r][q=c]
    f32x4 s[4];
    __builtin_amdgcn_s_setprio(1);
    #pragma unroll
    for (int sub = 0; sub < 4; sub++){
      int row = sub*16 + c;
      bf16x8 ka0 = *(const bf16x8*)&K_lds[cur][row][((0+g) ^ cswz)*8];
      bf16x8 ka1 = *(const bf16x8*)&K_lds[cur][row][((4+g) ^ cswz)*8];
      f32x4 z4 = {};
      z4 = mfma16(ka0, qf0, z4);
      z4 = mfma16(ka1, qf1, z4);
      s[sub] = z4;
    }
    __builtin_amdgcn_s_setprio(0);

    // scale + causal mask (actual key from permutation map)
    const bool edge = (kbase + 63 > qrow);
    const int q = qrow + c;
    #pragma unroll
    for (int sub = 0; sub < 4; sub++)
      #pragma unroll
      for (int r = 0; r < 4; r++){
        float v = s[sub][r]*0.125f;
        if (edge){
          int key = kbase + ((sub >> 1) << 5) + 8*g + ((sub & 1) << 2) + r;
          if (key > q) v = -1e30f;
        }
        s[sub][r] = v;
      }

    // online softmax: 16 in-lane values for query q=c; reduce across g via 2 shfl
    float tmax = s[0][0];
    #pragma unroll
    for (int sub = 0; sub < 4; sub++)
      #pragma unroll
      for (int r = 0; r < 4; r++) tmax = fmaxf(tmax, s[sub][r]);
    tmax = fmaxf(tmax, __shfl_xor(tmax, 16));
    tmax = fmaxf(tmax, __shfl_xor(tmax, 32));

    // defer-max (T13): only rescale when some row grew past m+8
    if (!__all(tmax <= m + 8.f)){
      float nm = fmaxf(m, tmax);
      float f = __expf(m - nm);
      m = nm;
      lsum *= f;
      float f_bc[4];
      #pragma unroll
      for (int r = 0; r < 4; r++) f_bc[r] = __shfl(f, 4*g + r);
      #pragma unroll
      for (int dt = 0; dt < 4; dt++)
        #pragma unroll
        for (int r = 0; r < 4; r++) accz[dt][r] *= f_bc[r];
    }

    float psum = 0.f;
    #pragma unroll
    for (int sub = 0; sub < 4; sub++)
      #pragma unroll
      for (int r = 0; r < 4; r++){
        float e = __expf(s[sub][r] - m);
        s[sub][r] = e;
        psum += e;
      }
    psum += __shfl_xor(psum, 16);
    psum += __shfl_xor(psum, 32);
    lsum += psum;

    // P -> bf16 A-frags, fully in-lane (keys 8g..8g+7 and 32+8g..+7)
    u32x4 p0, p1;
    p0[0] = pk2(s[0][0], s[0][1]); p0[1] = pk2(s[0][2], s[0][3]);
    p0[2] = pk2(s[1][0], s[1][1]); p0[3] = pk2(s[1][2], s[1][3]);
    p1[0] = pk2(s[2][0], s[2][1]); p1[1] = pk2(s[2][2], s[2][3]);
    p1[2] = pk2(s[3][0], s[3][1]); p1[3] = pk2(s[3][2], s[3][3]);
    bf16x8 pf0 = __builtin_bit_cast(bf16x8, p0);
    bf16x8 pf1 = __builtin_bit_cast(bf16x8, p1);

    // PV: Z[q=4g+r][d=dt*16+c] += P[q][k] V[k][d]
    __builtin_amdgcn_s_setprio(1);
    #pragma unroll
    for (int dt = 0; dt < 4; dt++){
      int vrow = dt*16 + c;
      bf16x8 vf0 = *(const bf16x8*)&V_lds[cur][vrow][((0+g) ^ cswz)*8];
      bf16x8 vf1 = *(const bf16x8*)&V_lds[cur][vrow][((4+g) ^ cswz)*8];
      accz[dt] = mfma16(pf0, vf0, accz[dt]);
      accz[dt] = mfma16(pf1, vf1, accz[dt]);
    }
    __builtin_amdgcn_s_setprio(0);

    if (t < ntiles-1){   // write next tile into the other buffer (no barrier needed)
      int nx = cur ^ 1;
      *(bf16x8*)&K_lds[nx][kpr0][(sch ^ (kpr0 & 7))*8] = kr;
      *(bf16x8*)&V_lds[nx][srow0][(sch ^ (srow0 & 7))*8] = vr;
      cur = nx;
    }
  }

  // epilogue: lsum lives at lane (*, q); broadcast to output-row owners
  float lsum_bc[4];
  #pragma unroll
  for (int r = 0; r < 4; r++) lsum_bc[r] = __shfl(lsum, 4*g + r);
  #pragma unroll
  for (int dt = 0; dt < 4; dt++)
    #pragma unroll
    for (int r = 0; r < 4; r++){
      float zv = accz[dt][r] / lsum_bc[r];
      int row = qrow + 4*g + r;
      int col = dt*16 + c;
      Z[(long)(b*SEQ + row)*DM + h*HD + col] = cvt1(zv);
    }
}

extern "C" void kernel_launch(void* const* d_in, const int* in_sizes, int n_in,
                              void* d_out, int out_size, void* d_ws, size_t ws_size,
                              hipStream_t stream)
{
  const float* x  = (const float*)d_in[0];
  const int*   pos= (const int*)d_in[1];
  const float* wq = (const float*)d_in[2];
  const float* wk = (const float*)d_in[3];
  const float* wv = (const float*)d_in[4];
  const float* wo = (const float*)d_in[5];
  float* out = (float*)d_out;

  const long NX = (long)MTOT*DM;
  const long NW = (long)DM*DM;
  char* p = (char*)d_ws;
  u16* xb   = (u16*)p;  p += NX*2;
  u16* wb   = (u16*)p;  p += 4*NW*2;
  u16* qkvr = (u16*)p;  p += 3*NX*2;
  u16* Qd   = (u16*)p;  p += NX*2;
  u16* Kd   = (u16*)p;  p += NX*2;
  u16* Vt   = (u16*)p;  p += NX*2;
  u16* Zb   = (u16*)p;  p += NX*2;
  float2* tab = (float2*)p; p += (long)SEQ*32*sizeof(float2);
  (void)ws_size; (void)n_in; (void)in_sizes; (void)out_size;

  hipLaunchKernelGGL(cvt_all,     dim3(2048),      dim3(256), 0, stream, x, wq, wk, wv, wo, xb, wb);
  hipLaunchKernelGGL(rope_table,  dim3(256),       dim3(256), 0, stream, tab);
  hipLaunchKernelGGL(gemm_qkv,    dim3(8,32,3),    dim3(256), 0, stream, xb, wb, qkvr);
  hipLaunchKernelGGL(rope_scatter,dim3(32,16,2),   dim3(256), 0, stream, qkvr, Qd, Kd, Vt, tab, pos);
  hipLaunchKernelGGL(attn,        dim3(16,16,2),   dim3(512), 0, stream, Qd, Kd, Vt, Zb);
  hipLaunchKernelGGL(gemm_out,    dim3(8,32),      dim3(256), 0, stream, Zb, wb + 3*NW, out);
}